// Round 6
// baseline (184.850 us; speedup 1.0000x reference)
//
#include <hip/hip_runtime.h>
#include <hip/hip_bf16.h>

// Distance-kernel attention, B=1, L=2048, D=768, H=12, dk=64.
// out0 [L,D] fp32 = context @ Wo^T + bo ; out1 [L,L] fp32 = mean_h attn_weights.
// All matmuls via mfma_f32_16x16x32_bf16, NT form, identical lane->k mapping on
// both operands (result independent of HW K-permutation).
// Attention passes use SWAPPED QK^T (A=K, B=Q): per-thread acc holds 4 contiguous
// j at fixed i -> packed LDS writes for W, f32x4 kn loads, f32x4 out1 stores,
// Q fragments live in registers. Loops that re-load operands per iteration use
// cooperative LDS staging + explicit register double-buffering (r3/r5 lesson).

typedef __bf16 bf16_t;
typedef bf16_t bf16x8 __attribute__((ext_vector_type(8)));
typedef bf16_t bf16x4 __attribute__((ext_vector_type(4)));
typedef float f32x4 __attribute__((ext_vector_type(4)));

#define L_SEQ 2048
#define DIM 768
#define NH 12
#define DKH 64
#define MDJ 4   // j-chunks in maxdist

__device__ __forceinline__ bf16x8 ldg8(const bf16_t* p) { return *(const bf16x8*)p; }
__device__ __forceinline__ f32x4 mfma16(bf16x8 a, bf16x8 b, f32x4 c_) {
  return __builtin_amdgcn_mfma_f32_16x16x32_bf16(a, b, c_, 0, 0, 0);
}

// ---- tile staging --------------------------------------------------------

struct Tile2 { bf16x8 r[2]; };

__device__ __forceinline__ void tile_load(const bf16_t* __restrict__ src, int stride,
                                          Tile2& t_, int tid) {
#pragma unroll
  for (int c = 0; c < 2; ++c) {
    int chunk = tid + c * 256;
    t_.r[c] = *(const bf16x8*)&src[(size_t)(chunk >> 3) * stride + (chunk & 7) * 8];
  }
}

__device__ __forceinline__ void tile_write(bf16_t (*dst)[72], const Tile2& t_, int tid) {
#pragma unroll
  for (int c = 0; c < 2; ++c) {
    int chunk = tid + c * 256;
    *(bf16x8*)&dst[chunk >> 3][(chunk & 7) * 8] = t_.r[c];
  }
}

__device__ __forceinline__ void mfma_nt64(bf16_t (*As)[72], bf16_t (*Bs)[72],
                                          int wid, int lane, f32x4 acc[4]) {
#pragma unroll
  for (int ks = 0; ks < 2; ++ks) {
    bf16x8 a = *(const bf16x8*)&As[wid * 16 + (lane & 15)][ks * 32 + (lane >> 4) * 8];
#pragma unroll
    for (int nt = 0; nt < 4; ++nt) {
      bf16x8 b = *(const bf16x8*)&Bs[nt * 16 + (lane & 15)][ks * 32 + (lane >> 4) * 8];
      acc[nt] = mfma16(a, b, acc[nt]);
    }
  }
}

// ---- casts ---------------------------------------------------------------

__global__ void cast_x(const float* __restrict__ in, bf16_t* __restrict__ out, int n4) {
  int i = blockIdx.x * 256 + threadIdx.x;
  if (i >= n4) return;
  float4 v = ((const float4*)in)[i];
  bf16_t* o = out + (size_t)i * 4;
  o[0] = (bf16_t)v.x; o[1] = (bf16_t)v.y; o[2] = (bf16_t)v.z; o[3] = (bf16_t)v.w;
}

__global__ void cast_w4(const float* __restrict__ w0, const float* __restrict__ w1,
                        const float* __restrict__ w2, const float* __restrict__ w3,
                        bf16_t* __restrict__ o0, bf16_t* __restrict__ o1,
                        bf16_t* __restrict__ o2, bf16_t* __restrict__ o3, int n4) {
  int i = blockIdx.x * 256 + threadIdx.x;
  if (i >= n4) return;
  const float* in = blockIdx.y == 0 ? w0 : blockIdx.y == 1 ? w1 : blockIdx.y == 2 ? w2 : w3;
  bf16_t* out = blockIdx.y == 0 ? o0 : blockIdx.y == 1 ? o1 : blockIdx.y == 2 ? o2 : o3;
  float4 v = ((const float4*)in)[i];
  bf16_t* o = out + (size_t)i * 4;
  o[0] = (bf16_t)v.x; o[1] = (bf16_t)v.y; o[2] = (bf16_t)v.z; o[3] = (bf16_t)v.w;
}

// ---- projections (double-buffered) ----------------------------------------

__global__ __launch_bounds__(256) void gemm_qkv(const bf16_t* __restrict__ x,
                                                const bf16_t* __restrict__ Bq,
                                                const bf16_t* __restrict__ Bk,
                                                const bf16_t* __restrict__ Bv,
                                                const float* __restrict__ bq,
                                                const float* __restrict__ bk,
                                                const float* __restrict__ bv,
                                                bf16_t* __restrict__ qo,
                                                bf16_t* __restrict__ ko,
                                                bf16_t* __restrict__ vto,
                                                float* __restrict__ qn,
                                                float* __restrict__ kn) {
  __shared__ bf16_t As[2][64][72];
  __shared__ bf16_t Bs[2][64][72];
  const int z = blockIdx.z;
  const bf16_t* B = z == 0 ? Bq : z == 1 ? Bk : Bv;
  const float* bias = z == 0 ? bq : z == 1 ? bk : bv;
  const int tid = threadIdx.x, wid = tid >> 6, lane = tid & 63;
  const int c = lane & 15, hi = lane >> 4;
  const int m0 = blockIdx.y * 64, n0 = blockIdx.x * 64;
  Tile2 at, bt;
  tile_load(x + (size_t)m0 * DIM, DIM, at, tid);
  tile_load(B + (size_t)n0 * DIM, DIM, bt, tid);
  f32x4 acc[4] = {};
  for (int kk = 0; kk < 12; ++kk) {
    tile_write(As[kk & 1], at, tid);
    tile_write(Bs[kk & 1], bt, tid);
    __syncthreads();
    if (kk < 11) {
      tile_load(x + (size_t)m0 * DIM + (kk + 1) * 64, DIM, at, tid);
      tile_load(B + (size_t)n0 * DIM + (kk + 1) * 64, DIM, bt, tid);
    }
    mfma_nt64(As[kk & 1], Bs[kk & 1], wid, lane, acc);
    __syncthreads();
  }
  const int r0 = wid * 16 + hi * 4;
  float ss[4] = {0.f, 0.f, 0.f, 0.f};
#pragma unroll
  for (int nt = 0; nt < 4; ++nt) {
    int cc = n0 + nt * 16 + c;
    float bv_ = bias[cc];
    int h = cc >> 6, d = cc & 63;
#pragma unroll
    for (int r = 0; r < 4; ++r) {
      int mm = m0 + r0 + r;
      float val = acc[nt][r] + bv_;
      if (z == 2) {
        vto[(size_t)cc * L_SEQ + mm] = (bf16_t)val;
      } else {
        bf16_t* out = z == 0 ? qo : ko;
        out[((size_t)h * L_SEQ + mm) * 64 + d] = (bf16_t)val;
        ss[r] = fmaf(val, val, ss[r]);
      }
    }
  }
  if (z < 2) {
#pragma unroll
    for (int s = 1; s < 16; s <<= 1)
#pragma unroll
      for (int r = 0; r < 4; ++r) ss[r] += __shfl_xor(ss[r], s);
    if (c == 0) {
      float* norm = z == 0 ? qn : kn;
      int h = n0 >> 6;
#pragma unroll
      for (int r = 0; r < 4; ++r) norm[h * L_SEQ + m0 + r0 + r] = ss[r];
    }
  }
}

__global__ __launch_bounds__(256) void gemm_out(const bf16_t* __restrict__ A,
                                                const bf16_t* __restrict__ B,
                                                const float* __restrict__ bias,
                                                float* __restrict__ out) {
  __shared__ bf16_t As[2][64][72];
  __shared__ bf16_t Bs[2][64][72];
  const int tid = threadIdx.x, wid = tid >> 6, lane = tid & 63;
  const int c = lane & 15, hi = lane >> 4;
  const int m0 = blockIdx.y * 64, n0 = blockIdx.x * 64;
  Tile2 at, bt;
  tile_load(A + (size_t)m0 * DIM, DIM, at, tid);
  tile_load(B + (size_t)n0 * DIM, DIM, bt, tid);
  f32x4 acc[4] = {};
  for (int kk = 0; kk < 12; ++kk) {
    tile_write(As[kk & 1], at, tid);
    tile_write(Bs[kk & 1], bt, tid);
    __syncthreads();
    if (kk < 11) {
      tile_load(A + (size_t)m0 * DIM + (kk + 1) * 64, DIM, at, tid);
      tile_load(B + (size_t)n0 * DIM + (kk + 1) * 64, DIM, bt, tid);
    }
    mfma_nt64(As[kk & 1], Bs[kk & 1], wid, lane, acc);
    __syncthreads();
  }
  const int r0 = wid * 16 + hi * 4;
#pragma unroll
  for (int nt = 0; nt < 4; ++nt) {
    int cc = n0 + nt * 16 + c;
    float bv = bias[cc];
#pragma unroll
    for (int r = 0; r < 4; ++r)
      out[(size_t)(m0 + r0 + r) * DIM + cc] = acc[nt][r] + bv;
  }
}

// ---- pass 1: global max of dist_sq (swapped QK, Q in regs) ---------------

__global__ __launch_bounds__(256) void maxdist(const bf16_t* __restrict__ q,
                                               const bf16_t* __restrict__ k,
                                               const float* __restrict__ qn,
                                               const float* __restrict__ kn,
                                               float* __restrict__ blockmax) {
  __shared__ bf16_t Ks[2][64][72];
  __shared__ float wmax[4];
  const int it = blockIdx.x, jc = blockIdx.y, h = blockIdx.z;
  const int i0 = it * 64, jbase = jc * (L_SEQ / MDJ);
  const int tid = threadIdx.x, wid = tid >> 6, lane = tid & 63;
  const int c = lane & 15, hi = lane >> 4;
  bf16x8 qb[4][2];
  float aq[4];
#pragma unroll
  for (int nt = 0; nt < 4; ++nt) {
    const bf16_t* qr = q + ((size_t)h * L_SEQ + i0 + nt * 16 + c) * DKH;
    qb[nt][0] = ldg8(qr + hi * 8);
    qb[nt][1] = ldg8(qr + 32 + hi * 8);
    aq[nt] = qn[h * L_SEQ + i0 + nt * 16 + c];
  }
  Tile2 kt;
  tile_load(k + ((size_t)h * L_SEQ + jbase) * DKH, DKH, kt, tid);
  float m = 0.f;
  const int NT = L_SEQ / MDJ / 64;
  for (int t = 0; t < NT; ++t) {
    tile_write(Ks[t & 1], kt, tid);
    if (t < NT - 1)
      tile_load(k + ((size_t)h * L_SEQ + jbase + (t + 1) * 64) * DKH, DKH, kt, tid);
    __syncthreads();
    f32x4 acc[4] = {};
#pragma unroll
    for (int ks = 0; ks < 2; ++ks) {
      bf16x8 a = *(const bf16x8*)&Ks[t & 1][wid * 16 + c][ks * 32 + hi * 8];
#pragma unroll
      for (int nt = 0; nt < 4; ++nt) acc[nt] = mfma16(a, qb[nt][ks], acc[nt]);
    }
    f32x4 knj = *(const f32x4*)&kn[h * L_SEQ + jbase + t * 64 + wid * 16 + hi * 4];
#pragma unroll
    for (int nt = 0; nt < 4; ++nt)
#pragma unroll
      for (int r = 0; r < 4; ++r)
        m = fmaxf(m, fmaf(-2.f, acc[nt][r], aq[nt] + knj[r]));
  }
#pragma unroll
  for (int s = 1; s < 64; s <<= 1) m = fmaxf(m, __shfl_xor(m, s));
  if (lane == 0) wmax[wid] = m;
  __syncthreads();
  if (tid == 0) {
    float bm = fmaxf(fmaxf(wmax[0], wmax[1]), fmaxf(wmax[2], wmax[3]));
    blockmax[(h * MDJ + jc) * (L_SEQ / 64) + it] = fmaxf(bm, 0.f) * (1.f / 64.f);
  }
}

__global__ void reduce_dmax(const float* __restrict__ blockmax, float* __restrict__ dmax) {
  __shared__ float wm[2];
  const int h = blockIdx.x, tid = threadIdx.x, lane = tid & 63, wid = tid >> 6;
  float m = blockmax[h * 128 + tid];
#pragma unroll
  for (int s = 1; s < 64; s <<= 1) m = fmaxf(m, __shfl_xor(m, s));
  if (lane == 0) wm[wid] = m;
  __syncthreads();
  if (tid == 0) dmax[h] = fmaxf(wm[0], wm[1]);
}

// ---- pass 2: partial den + partial ctx^T (swapped QK) --------------------

__global__ __launch_bounds__(256) void fusedctx(const bf16_t* __restrict__ q,
                                                const bf16_t* __restrict__ k,
                                                const bf16_t* __restrict__ vt,
                                                const float* __restrict__ qn,
                                                const float* __restrict__ kn,
                                                const float* __restrict__ dmax,
                                                const float* __restrict__ theta,
                                                float* __restrict__ denP,
                                                float* __restrict__ ctxP, int JC) {
  __shared__ bf16_t Ks[2][64][72];
  __shared__ bf16_t Vs[2][64][72];
  __shared__ bf16_t Ws[64][72];
  __shared__ float denW[4][64];
  const int it = blockIdx.x, jc = blockIdx.y, h = blockIdx.z;
  const int i0 = it * 64;
  const int JLEN = L_SEQ / JC, jbase = jc * JLEN;
  const int tid = threadIdx.x, wid = tid >> 6, lane = tid & 63;
  const int c = lane & 15, hi = lane >> 4;
  const float sc = __expf(theta[h]) * (1.f / 64.f) / (dmax[h] + 1e-6f);
  const float twosc = 2.f * sc;
  bf16x8 qb[4][2];
  float naq[4];
#pragma unroll
  for (int nt = 0; nt < 4; ++nt) {
    const bf16_t* qr = q + ((size_t)h * L_SEQ + i0 + nt * 16 + c) * DKH;
    qb[nt][0] = ldg8(qr + hi * 8);
    qb[nt][1] = ldg8(qr + 32 + hi * 8);
    naq[nt] = -sc * qn[h * L_SEQ + i0 + nt * 16 + c];
  }
  Tile2 kt, vtr;
  tile_load(k + ((size_t)h * L_SEQ + jbase) * DKH, DKH, kt, tid);
  tile_load(vt + (size_t)h * DKH * L_SEQ + jbase, L_SEQ, vtr, tid);
  float psum[4] = {0.f, 0.f, 0.f, 0.f};
  f32x4 cacc[4] = {};
  const int NT = JLEN / 64;
  for (int t = 0; t < NT; ++t) {
    tile_write(Ks[t & 1], kt, tid);
    tile_write(Vs[t & 1], vtr, tid);
    if (t < NT - 1) {
      tile_load(k + ((size_t)h * L_SEQ + jbase + (t + 1) * 64) * DKH, DKH, kt, tid);
      tile_load(vt + (size_t)h * DKH * L_SEQ + jbase + (t + 1) * 64, L_SEQ, vtr, tid);
    }
    __syncthreads();
    f32x4 acc[4] = {};
#pragma unroll
    for (int ks = 0; ks < 2; ++ks) {
      bf16x8 a = *(const bf16x8*)&Ks[t & 1][wid * 16 + c][ks * 32 + hi * 8];
#pragma unroll
      for (int nt = 0; nt < 4; ++nt) acc[nt] = mfma16(a, qb[nt][ks], acc[nt]);
    }
    f32x4 knj = *(const f32x4*)&kn[h * L_SEQ + jbase + t * 64 + wid * 16 + hi * 4];
    f32x4 sknj = knj * sc;
#pragma unroll
    for (int nt = 0; nt < 4; ++nt) {
      bf16x4 wp;
#pragma unroll
      for (int r = 0; r < 4; ++r) {
        float tt = fminf(fmaf(twosc, acc[nt][r], naq[nt] - sknj[r]), 0.f);
        float w = __expf(__expf(tt));      // in (0, e]
        psum[nt] += w;
        wp[r] = (bf16_t)w;
      }
      *(bf16x4*)&Ws[nt * 16 + c][wid * 16 + hi * 4] = wp;
    }
    __syncthreads();
#pragma unroll
    for (int ks = 0; ks < 2; ++ks) {
      bf16x8 a = *(const bf16x8*)&Vs[t & 1][wid * 16 + c][ks * 32 + hi * 8];
#pragma unroll
      for (int nt = 0; nt < 4; ++nt) {
        bf16x8 b = *(const bf16x8*)&Ws[nt * 16 + c][ks * 32 + hi * 8];
        cacc[nt] = mfma16(a, b, cacc[nt]);
      }
    }
  }
#pragma unroll
  for (int nt = 0; nt < 4; ++nt) {
    psum[nt] += __shfl_xor(psum[nt], 16);
    psum[nt] += __shfl_xor(psum[nt], 32);
  }
  if (lane < 16)
#pragma unroll
    for (int nt = 0; nt < 4; ++nt) denW[wid][nt * 16 + lane] = psum[nt];
  __syncthreads();
  if (tid < 64)
    denP[(size_t)(h * JC + jc) * L_SEQ + i0 + tid] =
        denW[0][tid] + denW[1][tid] + denW[2][tid] + denW[3][tid];
  float* P = ctxP + ((size_t)(h * JC + jc) * 32 + it) * 4096;
#pragma unroll
  for (int nt = 0; nt < 4; ++nt)
    *(f32x4*)&P[(nt * 16 + c) * 64 + wid * 16 + hi * 4] = cacc[nt];
}

__global__ __launch_bounds__(256) void ctx_combine(const float* __restrict__ denP,
                                                   const float* __restrict__ ctxP,
                                                   float* __restrict__ den,
                                                   bf16_t* __restrict__ ctx, int JC) {
  __shared__ float invL[64];
  const int it = blockIdx.x, h = blockIdx.y, tid = threadIdx.x;
  const int i0 = it * 64;
  if (tid < 64) {
    float d0 = 0.f;
    for (int jc = 0; jc < JC; ++jc)
      d0 += denP[(size_t)(h * JC + jc) * L_SEQ + i0 + tid];
    den[h * L_SEQ + i0 + tid] = d0;
    invL[tid] = 1.f / d0;
  }
  __syncthreads();
  const int il = tid >> 2, db = (tid & 3) * 16;
  const float inv = invL[il];
  bf16_t* dst = ctx + (size_t)(i0 + il) * DIM + h * 64 + db;
#pragma unroll
  for (int half = 0; half < 2; ++half) {
    bf16x8 o;
#pragma unroll
    for (int e = 0; e < 2; ++e) {
      f32x4 v = {0.f, 0.f, 0.f, 0.f};
      for (int jc = 0; jc < JC; ++jc)
        v += *(const f32x4*)&ctxP[((size_t)(h * JC + jc) * 32 + it) * 4096 +
                                  il * 64 + db + half * 8 + e * 4];
#pragma unroll
      for (int j = 0; j < 4; ++j) o[e * 4 + j] = (bf16_t)(v[j] * inv);
    }
    *(bf16x8*)&dst[half * 8] = o;
  }
}

// ---- pass 3: out1 = mean over heads (swapped, K LDS-staged, Q reg-dbuf) --

__device__ __forceinline__ void amean_head(
    int h, int i0, int j0, int tid, int wid, int c, int hi,
    const bf16_t* __restrict__ q, const bf16_t* __restrict__ k,
    const float* __restrict__ qn, const float* __restrict__ kn,
    const float* __restrict__ dmax, const float* __restrict__ theta,
    const float* __restrict__ den, bf16_t (*KsCur)[72],
    bf16x8 (&qcur)[4][2], bf16x8 (&qnxt)[4][2], Tile2& kt,
    f32x4 (&macc)[4], bool last) {
  tile_write(KsCur, kt, tid);
  __syncthreads();
  if (!last) {
    tile_load(k + ((size_t)(h + 1) * L_SEQ + j0) * DKH, DKH, kt, tid);
#pragma unroll
    for (int nt = 0; nt < 4; ++nt) {
      const bf16_t* qr = q + ((size_t)(h + 1) * L_SEQ + i0 + nt * 16 + c) * DKH;
      qnxt[nt][0] = ldg8(qr + hi * 8);
      qnxt[nt][1] = ldg8(qr + 32 + hi * 8);
    }
  }
  const float sc = __expf(theta[h]) * (1.f / 64.f) / (dmax[h] + 1e-6f);
  const float twosc = 2.f * sc;
  f32x4 acc[4] = {};
#pragma unroll
  for (int ks = 0; ks < 2; ++ks) {
    bf16x8 a = *(const bf16x8*)&KsCur[wid * 16 + c][ks * 32 + hi * 8];
#pragma unroll
    for (int nt = 0; nt < 4; ++nt) acc[nt] = mfma16(a, qcur[nt][ks], acc[nt]);
  }
  f32x4 knj = *(const f32x4*)&kn[h * L_SEQ + j0 + wid * 16 + hi * 4];
  f32x4 sknj = knj * sc;
#pragma unroll
  for (int nt = 0; nt < 4; ++nt) {
    float naq = -sc * qn[h * L_SEQ + i0 + nt * 16 + c];
    float inv = 1.f / den[h * L_SEQ + i0 + nt * 16 + c];
#pragma unroll
    for (int r = 0; r < 4; ++r) {
      float tt = fminf(fmaf(twosc, acc[nt][r], naq - sknj[r]), 0.f);
      float w = __expf(__expf(tt));
      macc[nt][r] = fmaf(w, inv, macc[nt][r]);
    }
  }
}

__global__ __launch_bounds__(256) void attnmean(const bf16_t* __restrict__ q,
                                                const bf16_t* __restrict__ k,
                                                const float* __restrict__ qn,
                                                const float* __restrict__ kn,
                                                const float* __restrict__ dmax,
                                                const float* __restrict__ theta,
                                                const float* __restrict__ den,
                                                float* __restrict__ out1) {
  __shared__ bf16_t Ks[2][64][72];
  const int j0 = blockIdx.x * 64, i0 = blockIdx.y * 64;
  const int tid = threadIdx.x, wid = tid >> 6, lane = tid & 63;
  const int c = lane & 15, hi = lane >> 4;
  Tile2 kt;
  bf16x8 qbA[4][2], qbB[4][2];
  tile_load(k + (size_t)j0 * DKH, DKH, kt, tid);     // h = 0
#pragma unroll
  for (int nt = 0; nt < 4; ++nt) {
    const bf16_t* qr = q + ((size_t)i0 + nt * 16 + c) * DKH;
    qbA[nt][0] = ldg8(qr + hi * 8);
    qbA[nt][1] = ldg8(qr + 32 + hi * 8);
  }
  f32x4 macc[4] = {};
  for (int h = 0; h < NH; h += 2) {
    amean_head(h, i0, j0, tid, wid, c, hi, q, k, qn, kn, dmax, theta, den,
               Ks[0], qbA, qbB, kt, macc, false);
    amean_head(h + 1, i0, j0, tid, wid, c, hi, q, k, qn, kn, dmax, theta, den,
               Ks[1], qbB, qbA, kt, macc, h + 1 == NH - 1);
  }
#pragma unroll
  for (int nt = 0; nt < 4; ++nt) {
    f32x4 o = macc[nt] * (1.f / 12.f);
    *(f32x4*)&out1[(size_t)(i0 + nt * 16 + c) * L_SEQ + j0 + wid * 16 + hi * 4] = o;
  }
}

// ---- launch -------------------------------------------------------------

extern "C" void kernel_launch(void* const* d_in, const int* in_sizes, int n_in,
                              void* d_out, int out_size, void* d_ws, size_t ws_size,
                              hipStream_t stream) {
  const float* x = (const float*)d_in[0];
  const float* Wq = (const float*)d_in[1];
  const float* bq = (const float*)d_in[2];
  const float* Wk = (const float*)d_in[3];
  const float* bk = (const float*)d_in[4];
  const float* Wv = (const float*)d_in[5];
  const float* bv = (const float*)d_in[6];
  const float* Wo = (const float*)d_in[7];
  const float* bo = (const float*)d_in[8];
  const float* theta = (const float*)d_in[9];

  bf16_t* x_bf = (bf16_t*)d_ws;
  bf16_t* Wq_bf = x_bf + (size_t)L_SEQ * DIM;
  bf16_t* Wk_bf = Wq_bf + (size_t)DIM * DIM;
  bf16_t* Wv_bf = Wk_bf + (size_t)DIM * DIM;
  bf16_t* Wo_bf = Wv_bf + (size_t)DIM * DIM;
  bf16_t* q_bf = Wo_bf + (size_t)DIM * DIM;
  bf16_t* k_bf = q_bf + (size_t)NH * L_SEQ * DKH;
  bf16_t* vt_bf = k_bf + (size_t)NH * L_SEQ * DKH;
  bf16_t* ctx_bf = vt_bf + (size_t)NH * L_SEQ * DKH;
  float* qn = (float*)(ctx_bf + (size_t)L_SEQ * DIM);
  float* kn = qn + NH * L_SEQ;
  float* den = kn + NH * L_SEQ;
  float* dmax = den + NH * L_SEQ;
  float* blockmax = dmax + 64;                 // NH*MDJ*32 = 1536
  float* denP = blockmax + 2048;               // JC*NH*L_SEQ <= 98304
  float* ctxP = denP + 4 * NH * L_SEQ;         // JC*NH*32*4096 fp32

  size_t fixed_bytes = (size_t)((char*)ctxP - (char*)d_ws);
  int JC = (fixed_bytes + (size_t)4 * NH * 32 * 4096 * 4 <= ws_size) ? 4 : 2;

  float* out0 = (float*)d_out;
  float* out1 = out0 + (size_t)L_SEQ * DIM;

  cast_x<<<(L_SEQ * DIM / 4 + 255) / 256, 256, 0, stream>>>(x, x_bf, L_SEQ * DIM / 4);
  cast_w4<<<dim3((DIM * DIM / 4 + 255) / 256, 4), 256, 0, stream>>>(
      Wq, Wk, Wv, Wo, Wq_bf, Wk_bf, Wv_bf, Wo_bf, DIM * DIM / 4);

  gemm_qkv<<<dim3(DIM / 64, L_SEQ / 64, 3), 256, 0, stream>>>(
      x_bf, Wq_bf, Wk_bf, Wv_bf, bq, bk, bv, q_bf, k_bf, vt_bf, qn, kn);

  maxdist<<<dim3(L_SEQ / 64, MDJ, NH), 256, 0, stream>>>(q_bf, k_bf, qn, kn, blockmax);
  reduce_dmax<<<NH, 128, 0, stream>>>(blockmax, dmax);

  fusedctx<<<dim3(L_SEQ / 64, JC, NH), 256, 0, stream>>>(q_bf, k_bf, vt_bf, qn, kn,
                                                         dmax, theta, denP, ctxP, JC);
  ctx_combine<<<dim3(L_SEQ / 64, NH), 256, 0, stream>>>(denP, ctxP, den, ctx_bf, JC);

  attnmean<<<dim3(L_SEQ / 64, L_SEQ / 64), 256, 0, stream>>>(q_bf, k_bf, qn, kn, dmax,
                                                             theta, den, out1);
  gemm_out<<<dim3(DIM / 64, L_SEQ / 64), 256, 0, stream>>>(ctx_bf, Wo_bf, bo, out0);
}

// Round 7
// 168.705 us; speedup vs baseline: 1.0957x; 1.0957x over previous
//
#include <hip/hip_runtime.h>
#include <hip/hip_bf16.h>

// Distance-kernel attention, B=1, L=2048, D=768, H=12, dk=64.
// out0 [L,D] fp32 = context @ Wo^T + bo ; out1 [L,L] fp32 = mean_h attn_weights.
// All matmuls via mfma_f32_16x16x32_bf16, NT form, identical lane->k mapping on
// both operands (result independent of HW K-permutation).
// Swapped QK^T (A=K, B=Q): per-thread acc holds 4 contiguous j at fixed i.
// attnmean: all 12 heads' K tiles staged ONCE (55 KB LDS), barrier-free head
// loop, 8-wave blocks -> latency hidden by TLP+ILP instead of barriers.

typedef __bf16 bf16_t;
typedef bf16_t bf16x8 __attribute__((ext_vector_type(8)));
typedef bf16_t bf16x4 __attribute__((ext_vector_type(4)));
typedef float f32x4 __attribute__((ext_vector_type(4)));

#define L_SEQ 2048
#define DIM 768
#define NH 12
#define DKH 64
#define MDJ 4   // j-chunks in maxdist

__device__ __forceinline__ bf16x8 ldg8(const bf16_t* p) { return *(const bf16x8*)p; }
__device__ __forceinline__ f32x4 mfma16(bf16x8 a, bf16x8 b, f32x4 c_) {
  return __builtin_amdgcn_mfma_f32_16x16x32_bf16(a, b, c_, 0, 0, 0);
}

// ---- tile staging --------------------------------------------------------

struct Tile2 { bf16x8 r[2]; };

__device__ __forceinline__ void tile_load(const bf16_t* __restrict__ src, int stride,
                                          Tile2& t_, int tid) {
#pragma unroll
  for (int c = 0; c < 2; ++c) {
    int chunk = tid + c * 256;
    t_.r[c] = *(const bf16x8*)&src[(size_t)(chunk >> 3) * stride + (chunk & 7) * 8];
  }
}

__device__ __forceinline__ void tile_write(bf16_t (*dst)[72], const Tile2& t_, int tid) {
#pragma unroll
  for (int c = 0; c < 2; ++c) {
    int chunk = tid + c * 256;
    *(bf16x8*)&dst[chunk >> 3][(chunk & 7) * 8] = t_.r[c];
  }
}

__device__ __forceinline__ void mfma_nt64(bf16_t (*As)[72], bf16_t (*Bs)[72],
                                          int wid, int lane, f32x4 acc[4]) {
#pragma unroll
  for (int ks = 0; ks < 2; ++ks) {
    bf16x8 a = *(const bf16x8*)&As[wid * 16 + (lane & 15)][ks * 32 + (lane >> 4) * 8];
#pragma unroll
    for (int nt = 0; nt < 4; ++nt) {
      bf16x8 b = *(const bf16x8*)&Bs[nt * 16 + (lane & 15)][ks * 32 + (lane >> 4) * 8];
      acc[nt] = mfma16(a, b, acc[nt]);
    }
  }
}

// ---- casts ---------------------------------------------------------------

__global__ void cast_x(const float* __restrict__ in, bf16_t* __restrict__ out, int n4) {
  int i = blockIdx.x * 256 + threadIdx.x;
  if (i >= n4) return;
  float4 v = ((const float4*)in)[i];
  bf16_t* o = out + (size_t)i * 4;
  o[0] = (bf16_t)v.x; o[1] = (bf16_t)v.y; o[2] = (bf16_t)v.z; o[3] = (bf16_t)v.w;
}

__global__ void cast_w4(const float* __restrict__ w0, const float* __restrict__ w1,
                        const float* __restrict__ w2, const float* __restrict__ w3,
                        bf16_t* __restrict__ o0, bf16_t* __restrict__ o1,
                        bf16_t* __restrict__ o2, bf16_t* __restrict__ o3, int n4) {
  int i = blockIdx.x * 256 + threadIdx.x;
  if (i >= n4) return;
  const float* in = blockIdx.y == 0 ? w0 : blockIdx.y == 1 ? w1 : blockIdx.y == 2 ? w2 : w3;
  bf16_t* out = blockIdx.y == 0 ? o0 : blockIdx.y == 1 ? o1 : blockIdx.y == 2 ? o2 : o3;
  float4 v = ((const float4*)in)[i];
  bf16_t* o = out + (size_t)i * 4;
  o[0] = (bf16_t)v.x; o[1] = (bf16_t)v.y; o[2] = (bf16_t)v.z; o[3] = (bf16_t)v.w;
}

// ---- projections (double-buffered) ----------------------------------------

__global__ __launch_bounds__(256) void gemm_qkv(const bf16_t* __restrict__ x,
                                                const bf16_t* __restrict__ Bq,
                                                const bf16_t* __restrict__ Bk,
                                                const bf16_t* __restrict__ Bv,
                                                const float* __restrict__ bq,
                                                const float* __restrict__ bk,
                                                const float* __restrict__ bv,
                                                bf16_t* __restrict__ qo,
                                                bf16_t* __restrict__ ko,
                                                bf16_t* __restrict__ vto,
                                                float* __restrict__ qn,
                                                float* __restrict__ kn) {
  __shared__ bf16_t As[2][64][72];
  __shared__ bf16_t Bs[2][64][72];
  const int z = blockIdx.z;
  const bf16_t* B = z == 0 ? Bq : z == 1 ? Bk : Bv;
  const float* bias = z == 0 ? bq : z == 1 ? bk : bv;
  const int tid = threadIdx.x, wid = tid >> 6, lane = tid & 63;
  const int c = lane & 15, hi = lane >> 4;
  const int m0 = blockIdx.y * 64, n0 = blockIdx.x * 64;
  Tile2 at, bt;
  tile_load(x + (size_t)m0 * DIM, DIM, at, tid);
  tile_load(B + (size_t)n0 * DIM, DIM, bt, tid);
  f32x4 acc[4] = {};
  for (int kk = 0; kk < 12; ++kk) {
    tile_write(As[kk & 1], at, tid);
    tile_write(Bs[kk & 1], bt, tid);
    __syncthreads();
    if (kk < 11) {
      tile_load(x + (size_t)m0 * DIM + (kk + 1) * 64, DIM, at, tid);
      tile_load(B + (size_t)n0 * DIM + (kk + 1) * 64, DIM, bt, tid);
    }
    mfma_nt64(As[kk & 1], Bs[kk & 1], wid, lane, acc);
    __syncthreads();
  }
  const int r0 = wid * 16 + hi * 4;
  float ss[4] = {0.f, 0.f, 0.f, 0.f};
#pragma unroll
  for (int nt = 0; nt < 4; ++nt) {
    int cc = n0 + nt * 16 + c;
    float bv_ = bias[cc];
    int h = cc >> 6, d = cc & 63;
#pragma unroll
    for (int r = 0; r < 4; ++r) {
      int mm = m0 + r0 + r;
      float val = acc[nt][r] + bv_;
      if (z == 2) {
        vto[(size_t)cc * L_SEQ + mm] = (bf16_t)val;
      } else {
        bf16_t* out = z == 0 ? qo : ko;
        out[((size_t)h * L_SEQ + mm) * 64 + d] = (bf16_t)val;
        ss[r] = fmaf(val, val, ss[r]);
      }
    }
  }
  if (z < 2) {
#pragma unroll
    for (int s = 1; s < 16; s <<= 1)
#pragma unroll
      for (int r = 0; r < 4; ++r) ss[r] += __shfl_xor(ss[r], s);
    if (c == 0) {
      float* norm = z == 0 ? qn : kn;
      int h = n0 >> 6;
#pragma unroll
      for (int r = 0; r < 4; ++r) norm[h * L_SEQ + m0 + r0 + r] = ss[r];
    }
  }
}

__global__ __launch_bounds__(256) void gemm_out(const bf16_t* __restrict__ A,
                                                const bf16_t* __restrict__ B,
                                                const float* __restrict__ bias,
                                                float* __restrict__ out) {
  __shared__ bf16_t As[2][64][72];
  __shared__ bf16_t Bs[2][64][72];
  const int tid = threadIdx.x, wid = tid >> 6, lane = tid & 63;
  const int c = lane & 15, hi = lane >> 4;
  const int m0 = blockIdx.y * 64, n0 = blockIdx.x * 64;
  Tile2 at, bt;
  tile_load(A + (size_t)m0 * DIM, DIM, at, tid);
  tile_load(B + (size_t)n0 * DIM, DIM, bt, tid);
  f32x4 acc[4] = {};
  for (int kk = 0; kk < 12; ++kk) {
    tile_write(As[kk & 1], at, tid);
    tile_write(Bs[kk & 1], bt, tid);
    __syncthreads();
    if (kk < 11) {
      tile_load(A + (size_t)m0 * DIM + (kk + 1) * 64, DIM, at, tid);
      tile_load(B + (size_t)n0 * DIM + (kk + 1) * 64, DIM, bt, tid);
    }
    mfma_nt64(As[kk & 1], Bs[kk & 1], wid, lane, acc);
    __syncthreads();
  }
  const int r0 = wid * 16 + hi * 4;
#pragma unroll
  for (int nt = 0; nt < 4; ++nt) {
    int cc = n0 + nt * 16 + c;
    float bv = bias[cc];
#pragma unroll
    for (int r = 0; r < 4; ++r)
      out[(size_t)(m0 + r0 + r) * DIM + cc] = acc[nt][r] + bv;
  }
}

// ---- pass 1: global max of dist_sq (swapped QK, Q in regs) ---------------

__global__ __launch_bounds__(256) void maxdist(const bf16_t* __restrict__ q,
                                               const bf16_t* __restrict__ k,
                                               const float* __restrict__ qn,
                                               const float* __restrict__ kn,
                                               float* __restrict__ blockmax) {
  __shared__ bf16_t Ks[2][64][72];
  __shared__ float wmax[4];
  const int it = blockIdx.x, jc = blockIdx.y, h = blockIdx.z;
  const int i0 = it * 64, jbase = jc * (L_SEQ / MDJ);
  const int tid = threadIdx.x, wid = tid >> 6, lane = tid & 63;
  const int c = lane & 15, hi = lane >> 4;
  bf16x8 qb[4][2];
  float aq[4];
#pragma unroll
  for (int nt = 0; nt < 4; ++nt) {
    const bf16_t* qr = q + ((size_t)h * L_SEQ + i0 + nt * 16 + c) * DKH;
    qb[nt][0] = ldg8(qr + hi * 8);
    qb[nt][1] = ldg8(qr + 32 + hi * 8);
    aq[nt] = qn[h * L_SEQ + i0 + nt * 16 + c];
  }
  Tile2 kt;
  tile_load(k + ((size_t)h * L_SEQ + jbase) * DKH, DKH, kt, tid);
  float m = 0.f;
  const int NT = L_SEQ / MDJ / 64;
  for (int t = 0; t < NT; ++t) {
    tile_write(Ks[t & 1], kt, tid);
    if (t < NT - 1)
      tile_load(k + ((size_t)h * L_SEQ + jbase + (t + 1) * 64) * DKH, DKH, kt, tid);
    __syncthreads();
    f32x4 acc[4] = {};
#pragma unroll
    for (int ks = 0; ks < 2; ++ks) {
      bf16x8 a = *(const bf16x8*)&Ks[t & 1][wid * 16 + c][ks * 32 + hi * 8];
#pragma unroll
      for (int nt = 0; nt < 4; ++nt) acc[nt] = mfma16(a, qb[nt][ks], acc[nt]);
    }
    f32x4 knj = *(const f32x4*)&kn[h * L_SEQ + jbase + t * 64 + wid * 16 + hi * 4];
#pragma unroll
    for (int nt = 0; nt < 4; ++nt)
#pragma unroll
      for (int r = 0; r < 4; ++r)
        m = fmaxf(m, fmaf(-2.f, acc[nt][r], aq[nt] + knj[r]));
  }
#pragma unroll
  for (int s = 1; s < 64; s <<= 1) m = fmaxf(m, __shfl_xor(m, s));
  if (lane == 0) wmax[wid] = m;
  __syncthreads();
  if (tid == 0) {
    float bm = fmaxf(fmaxf(wmax[0], wmax[1]), fmaxf(wmax[2], wmax[3]));
    blockmax[(h * MDJ + jc) * (L_SEQ / 64) + it] = fmaxf(bm, 0.f) * (1.f / 64.f);
  }
}

__global__ void reduce_dmax(const float* __restrict__ blockmax, float* __restrict__ dmax) {
  __shared__ float wm[2];
  const int h = blockIdx.x, tid = threadIdx.x, lane = tid & 63, wid = tid >> 6;
  float m = blockmax[h * 128 + tid];
#pragma unroll
  for (int s = 1; s < 64; s <<= 1) m = fmaxf(m, __shfl_xor(m, s));
  if (lane == 0) wm[wid] = m;
  __syncthreads();
  if (tid == 0) dmax[h] = fmaxf(wm[0], wm[1]);
}

// ---- pass 2: partial den + partial ctx^T (swapped QK) --------------------

__global__ __launch_bounds__(256) void fusedctx(const bf16_t* __restrict__ q,
                                                const bf16_t* __restrict__ k,
                                                const bf16_t* __restrict__ vt,
                                                const float* __restrict__ qn,
                                                const float* __restrict__ kn,
                                                const float* __restrict__ dmax,
                                                const float* __restrict__ theta,
                                                float* __restrict__ denP,
                                                float* __restrict__ ctxP, int JC) {
  __shared__ bf16_t Ks[2][64][72];
  __shared__ bf16_t Vs[2][64][72];
  __shared__ bf16_t Ws[64][72];
  __shared__ float denW[4][64];
  const int it = blockIdx.x, jc = blockIdx.y, h = blockIdx.z;
  const int i0 = it * 64;
  const int JLEN = L_SEQ / JC, jbase = jc * JLEN;
  const int tid = threadIdx.x, wid = tid >> 6, lane = tid & 63;
  const int c = lane & 15, hi = lane >> 4;
  const float sc = __expf(theta[h]) * (1.f / 64.f) / (dmax[h] + 1e-6f);
  const float twosc = 2.f * sc;
  bf16x8 qb[4][2];
  float naq[4];
#pragma unroll
  for (int nt = 0; nt < 4; ++nt) {
    const bf16_t* qr = q + ((size_t)h * L_SEQ + i0 + nt * 16 + c) * DKH;
    qb[nt][0] = ldg8(qr + hi * 8);
    qb[nt][1] = ldg8(qr + 32 + hi * 8);
    naq[nt] = -sc * qn[h * L_SEQ + i0 + nt * 16 + c];
  }
  Tile2 kt, vtr;
  tile_load(k + ((size_t)h * L_SEQ + jbase) * DKH, DKH, kt, tid);
  tile_load(vt + (size_t)h * DKH * L_SEQ + jbase, L_SEQ, vtr, tid);
  float psum[4] = {0.f, 0.f, 0.f, 0.f};
  f32x4 cacc[4] = {};
  const int NT = JLEN / 64;
  for (int t = 0; t < NT; ++t) {
    tile_write(Ks[t & 1], kt, tid);
    tile_write(Vs[t & 1], vtr, tid);
    if (t < NT - 1) {
      tile_load(k + ((size_t)h * L_SEQ + jbase + (t + 1) * 64) * DKH, DKH, kt, tid);
      tile_load(vt + (size_t)h * DKH * L_SEQ + jbase + (t + 1) * 64, L_SEQ, vtr, tid);
    }
    __syncthreads();
    f32x4 acc[4] = {};
#pragma unroll
    for (int ks = 0; ks < 2; ++ks) {
      bf16x8 a = *(const bf16x8*)&Ks[t & 1][wid * 16 + c][ks * 32 + hi * 8];
#pragma unroll
      for (int nt = 0; nt < 4; ++nt) acc[nt] = mfma16(a, qb[nt][ks], acc[nt]);
    }
    f32x4 knj = *(const f32x4*)&kn[h * L_SEQ + jbase + t * 64 + wid * 16 + hi * 4];
    f32x4 sknj = knj * sc;
#pragma unroll
    for (int nt = 0; nt < 4; ++nt) {
      bf16x4 wp;
#pragma unroll
      for (int r = 0; r < 4; ++r) {
        float tt = fminf(fmaf(twosc, acc[nt][r], naq[nt] - sknj[r]), 0.f);
        float w = __expf(__expf(tt));      // in (0, e]
        psum[nt] += w;
        wp[r] = (bf16_t)w;
      }
      *(bf16x4*)&Ws[nt * 16 + c][wid * 16 + hi * 4] = wp;
    }
    __syncthreads();
#pragma unroll
    for (int ks = 0; ks < 2; ++ks) {
      bf16x8 a = *(const bf16x8*)&Vs[t & 1][wid * 16 + c][ks * 32 + hi * 8];
#pragma unroll
      for (int nt = 0; nt < 4; ++nt) {
        bf16x8 b = *(const bf16x8*)&Ws[nt * 16 + c][ks * 32 + hi * 8];
        cacc[nt] = mfma16(a, b, cacc[nt]);
      }
    }
  }
#pragma unroll
  for (int nt = 0; nt < 4; ++nt) {
    psum[nt] += __shfl_xor(psum[nt], 16);
    psum[nt] += __shfl_xor(psum[nt], 32);
  }
  if (lane < 16)
#pragma unroll
    for (int nt = 0; nt < 4; ++nt) denW[wid][nt * 16 + lane] = psum[nt];
  __syncthreads();
  if (tid < 64)
    denP[(size_t)(h * JC + jc) * L_SEQ + i0 + tid] =
        denW[0][tid] + denW[1][tid] + denW[2][tid] + denW[3][tid];
  float* P = ctxP + ((size_t)(h * JC + jc) * 32 + it) * 4096;
#pragma unroll
  for (int nt = 0; nt < 4; ++nt)
    *(f32x4*)&P[(nt * 16 + c) * 64 + wid * 16 + hi * 4] = cacc[nt];
}

__global__ __launch_bounds__(256) void ctx_combine(const float* __restrict__ denP,
                                                   const float* __restrict__ ctxP,
                                                   float* __restrict__ den,
                                                   bf16_t* __restrict__ ctx, int JC) {
  __shared__ float invL[64];
  const int it = blockIdx.x, h = blockIdx.y, tid = threadIdx.x;
  const int i0 = it * 64;
  if (tid < 64) {
    float d0 = 0.f;
    for (int jc = 0; jc < JC; ++jc)
      d0 += denP[(size_t)(h * JC + jc) * L_SEQ + i0 + tid];
    den[h * L_SEQ + i0 + tid] = d0;
    invL[tid] = 1.f / d0;
  }
  __syncthreads();
  const int il = tid >> 2, db = (tid & 3) * 16;
  const float inv = invL[il];
  bf16_t* dst = ctx + (size_t)(i0 + il) * DIM + h * 64 + db;
#pragma unroll
  for (int half = 0; half < 2; ++half) {
    bf16x8 o;
#pragma unroll
    for (int e = 0; e < 2; ++e) {
      f32x4 v = {0.f, 0.f, 0.f, 0.f};
      for (int jc = 0; jc < JC; ++jc)
        v += *(const f32x4*)&ctxP[((size_t)(h * JC + jc) * 32 + it) * 4096 +
                                  il * 64 + db + half * 8 + e * 4];
#pragma unroll
      for (int j = 0; j < 4; ++j) o[e * 4 + j] = (bf16_t)(v[j] * inv);
    }
    *(bf16x8*)&dst[half * 8] = o;
  }
}

// ---- pass 3: out1 = mean over heads --------------------------------------
// All 12 heads' K tiles (32 j-rows each) staged once: 12*32*72*2B = 55.3 KB LDS.
// 512 thr = 8 waves (2 j-strips x 4 i-quarters), block = 32 j x 256 i.
// ONE barrier; head loop is barrier-free -> TLP (16 waves/CU) + ILP hide latency.
__global__ __launch_bounds__(512) void attnmean(const bf16_t* __restrict__ q,
                                                const bf16_t* __restrict__ k,
                                                const float* __restrict__ qn,
                                                const float* __restrict__ kn,
                                                const float* __restrict__ dmax,
                                                const float* __restrict__ theta,
                                                const float* __restrict__ den,
                                                float* __restrict__ out1) {
  __shared__ bf16_t Ks[NH][32][72];
  const int j0 = blockIdx.x * 32, i0 = blockIdx.y * 256;
  const int tid = threadIdx.x, wid = tid >> 6, lane = tid & 63;
  const int c = lane & 15, hi = lane >> 4;
  const int js = wid & 1, ih = wid >> 1;     // j-strip (0..1), i-quarter (0..3)
  // stage all 12 K tiles: 512 threads cover 2 tiles per step (256 chunks each)
  {
    const int row = (tid & 255) >> 3, col = (tid & 7) * 8, tpl = tid >> 8;
#pragma unroll
    for (int t = 0; t < 6; ++t) {
      const int h = 2 * t + tpl;
      bf16x8 v = ldg8(k + ((size_t)h * L_SEQ + j0 + row) * DKH + col);
      *(bf16x8*)&Ks[h][row][col] = v;
    }
  }
  __syncthreads();
  const int ib = i0 + ih * 64;
  f32x4 macc[4] = {};
#pragma unroll 2
  for (int h = 0; h < NH; ++h) {
    const float sc = __expf(theta[h]) * (1.f / 64.f) / (dmax[h] + 1e-6f);
    const float twosc = 2.f * sc;
    bf16x8 qb[4][2];
#pragma unroll
    for (int nt = 0; nt < 4; ++nt) {
      const bf16_t* qr = q + ((size_t)h * L_SEQ + ib + nt * 16 + c) * DKH;
      qb[nt][0] = ldg8(qr + hi * 8);
      qb[nt][1] = ldg8(qr + 32 + hi * 8);
    }
    f32x4 acc[4] = {};
#pragma unroll
    for (int ks = 0; ks < 2; ++ks) {
      bf16x8 a = *(const bf16x8*)&Ks[h][js * 16 + c][ks * 32 + hi * 8];
#pragma unroll
      for (int nt = 0; nt < 4; ++nt) acc[nt] = mfma16(a, qb[nt][ks], acc[nt]);
    }
    f32x4 knj = *(const f32x4*)&kn[h * L_SEQ + j0 + js * 16 + hi * 4];
    f32x4 sknj = knj * sc;
#pragma unroll
    for (int nt = 0; nt < 4; ++nt) {
      float naq = -sc * qn[h * L_SEQ + ib + nt * 16 + c];
      float inv = 1.f / den[h * L_SEQ + ib + nt * 16 + c];
#pragma unroll
      for (int r = 0; r < 4; ++r) {
        float tt = fminf(fmaf(twosc, acc[nt][r], naq - sknj[r]), 0.f);
        float w = __expf(__expf(tt));
        macc[nt][r] = fmaf(w, inv, macc[nt][r]);
      }
    }
  }
#pragma unroll
  for (int nt = 0; nt < 4; ++nt) {
    f32x4 o = macc[nt] * (1.f / 12.f);
    *(f32x4*)&out1[(size_t)(ib + nt * 16 + c) * L_SEQ + j0 + js * 16 + hi * 4] = o;
  }
}

// ---- launch -------------------------------------------------------------

extern "C" void kernel_launch(void* const* d_in, const int* in_sizes, int n_in,
                              void* d_out, int out_size, void* d_ws, size_t ws_size,
                              hipStream_t stream) {
  const float* x = (const float*)d_in[0];
  const float* Wq = (const float*)d_in[1];
  const float* bq = (const float*)d_in[2];
  const float* Wk = (const float*)d_in[3];
  const float* bk = (const float*)d_in[4];
  const float* Wv = (const float*)d_in[5];
  const float* bv = (const float*)d_in[6];
  const float* Wo = (const float*)d_in[7];
  const float* bo = (const float*)d_in[8];
  const float* theta = (const float*)d_in[9];

  bf16_t* x_bf = (bf16_t*)d_ws;
  bf16_t* Wq_bf = x_bf + (size_t)L_SEQ * DIM;
  bf16_t* Wk_bf = Wq_bf + (size_t)DIM * DIM;
  bf16_t* Wv_bf = Wk_bf + (size_t)DIM * DIM;
  bf16_t* Wo_bf = Wv_bf + (size_t)DIM * DIM;
  bf16_t* q_bf = Wo_bf + (size_t)DIM * DIM;
  bf16_t* k_bf = q_bf + (size_t)NH * L_SEQ * DKH;
  bf16_t* vt_bf = k_bf + (size_t)NH * L_SEQ * DKH;
  bf16_t* ctx_bf = vt_bf + (size_t)NH * L_SEQ * DKH;
  float* qn = (float*)(ctx_bf + (size_t)L_SEQ * DIM);
  float* kn = qn + NH * L_SEQ;
  float* den = kn + NH * L_SEQ;
  float* dmax = den + NH * L_SEQ;
  float* blockmax = dmax + 64;                 // NH*MDJ*32 = 1536
  float* denP = blockmax + 2048;               // JC*NH*L_SEQ <= 98304
  float* ctxP = denP + 4 * NH * L_SEQ;         // JC*NH*32*4096 fp32

  size_t fixed_bytes = (size_t)((char*)ctxP - (char*)d_ws);
  int JC = (fixed_bytes + (size_t)4 * NH * 32 * 4096 * 4 <= ws_size) ? 4 : 2;

  float* out0 = (float*)d_out;
  float* out1 = out0 + (size_t)L_SEQ * DIM;

  cast_x<<<(L_SEQ * DIM / 4 + 255) / 256, 256, 0, stream>>>(x, x_bf, L_SEQ * DIM / 4);
  cast_w4<<<dim3((DIM * DIM / 4 + 255) / 256, 4), 256, 0, stream>>>(
      Wq, Wk, Wv, Wo, Wq_bf, Wk_bf, Wv_bf, Wo_bf, DIM * DIM / 4);

  gemm_qkv<<<dim3(DIM / 64, L_SEQ / 64, 3), 256, 0, stream>>>(
      x_bf, Wq_bf, Wk_bf, Wv_bf, bq, bk, bv, q_bf, k_bf, vt_bf, qn, kn);

  maxdist<<<dim3(L_SEQ / 64, MDJ, NH), 256, 0, stream>>>(q_bf, k_bf, qn, kn, blockmax);
  reduce_dmax<<<NH, 128, 0, stream>>>(blockmax, dmax);

  fusedctx<<<dim3(L_SEQ / 64, JC, NH), 256, 0, stream>>>(q_bf, k_bf, vt_bf, qn, kn,
                                                         dmax, theta, denP, ctxP, JC);
  ctx_combine<<<dim3(L_SEQ / 64, NH), 256, 0, stream>>>(denP, ctxP, den, ctx_bf, JC);

  attnmean<<<dim3(L_SEQ / 32, L_SEQ / 256), 512, 0, stream>>>(q_bf, k_bf, qn, kn, dmax,
                                                              theta, den, out1);
  gemm_out<<<dim3(DIM / 64, L_SEQ / 64), 256, 0, stream>>>(ctx_bf, Wo_bf, bo, out0);
}

// Round 8
// 142.179 us; speedup vs baseline: 1.3001x; 1.1866x over previous
//
#include <hip/hip_runtime.h>
#include <hip/hip_bf16.h>

// Distance-kernel attention, B=1, L=2048, D=768, H=12, dk=64.
// out0 [L,D] fp32 = context @ Wo^T + bo ; out1 [L,L] fp32 = mean_h attn_weights.
// All matmuls via mfma_f32_16x16x32_bf16, NT form, identical lane->k mapping on
// both operands (result independent of HW K-permutation).
// Swapped QK^T (A=K, B=Q): per-thread acc holds 4 contiguous j at fixed i.
// Proven structure (r2/r4): cooperative LDS staging of BOTH operands +
// register-prefetch double-buffering + >=4 blocks/CU. Per-thread global
// fragment loads inside loops are the anti-pattern on this chip (r3/r5/r7).

typedef __bf16 bf16_t;
typedef bf16_t bf16x8 __attribute__((ext_vector_type(8)));
typedef bf16_t bf16x4 __attribute__((ext_vector_type(4)));
typedef float f32x4 __attribute__((ext_vector_type(4)));

#define L_SEQ 2048
#define DIM 768
#define NH 12
#define DKH 64
#define MDJ 4   // j-chunks in maxdist

__device__ __forceinline__ bf16x8 ldg8(const bf16_t* p) { return *(const bf16x8*)p; }
__device__ __forceinline__ f32x4 mfma16(bf16x8 a, bf16x8 b, f32x4 c_) {
  return __builtin_amdgcn_mfma_f32_16x16x32_bf16(a, b, c_, 0, 0, 0);
}

// ---- tile staging --------------------------------------------------------

struct Tile2 { bf16x8 r[2]; };

__device__ __forceinline__ void tile_load(const bf16_t* __restrict__ src, int stride,
                                          Tile2& t_, int tid) {
#pragma unroll
  for (int c = 0; c < 2; ++c) {
    int chunk = tid + c * 256;
    t_.r[c] = *(const bf16x8*)&src[(size_t)(chunk >> 3) * stride + (chunk & 7) * 8];
  }
}

__device__ __forceinline__ void tile_write(bf16_t (*dst)[72], const Tile2& t_, int tid) {
#pragma unroll
  for (int c = 0; c < 2; ++c) {
    int chunk = tid + c * 256;
    *(bf16x8*)&dst[chunk >> 3][(chunk & 7) * 8] = t_.r[c];
  }
}

__device__ __forceinline__ void mfma_nt64(bf16_t (*As)[72], bf16_t (*Bs)[72],
                                          int wid, int lane, f32x4 acc[4]) {
#pragma unroll
  for (int ks = 0; ks < 2; ++ks) {
    bf16x8 a = *(const bf16x8*)&As[wid * 16 + (lane & 15)][ks * 32 + (lane >> 4) * 8];
#pragma unroll
    for (int nt = 0; nt < 4; ++nt) {
      bf16x8 b = *(const bf16x8*)&Bs[nt * 16 + (lane & 15)][ks * 32 + (lane >> 4) * 8];
      acc[nt] = mfma16(a, b, acc[nt]);
    }
  }
}

// ---- casts ---------------------------------------------------------------

__global__ void cast_x(const float* __restrict__ in, bf16_t* __restrict__ out, int n4) {
  int i = blockIdx.x * 256 + threadIdx.x;
  if (i >= n4) return;
  float4 v = ((const float4*)in)[i];
  bf16_t* o = out + (size_t)i * 4;
  o[0] = (bf16_t)v.x; o[1] = (bf16_t)v.y; o[2] = (bf16_t)v.z; o[3] = (bf16_t)v.w;
}

__global__ void cast_w4(const float* __restrict__ w0, const float* __restrict__ w1,
                        const float* __restrict__ w2, const float* __restrict__ w3,
                        bf16_t* __restrict__ o0, bf16_t* __restrict__ o1,
                        bf16_t* __restrict__ o2, bf16_t* __restrict__ o3, int n4) {
  int i = blockIdx.x * 256 + threadIdx.x;
  if (i >= n4) return;
  const float* in = blockIdx.y == 0 ? w0 : blockIdx.y == 1 ? w1 : blockIdx.y == 2 ? w2 : w3;
  bf16_t* out = blockIdx.y == 0 ? o0 : blockIdx.y == 1 ? o1 : blockIdx.y == 2 ? o2 : o3;
  float4 v = ((const float4*)in)[i];
  bf16_t* o = out + (size_t)i * 4;
  o[0] = (bf16_t)v.x; o[1] = (bf16_t)v.y; o[2] = (bf16_t)v.z; o[3] = (bf16_t)v.w;
}

// ---- projections (double-buffered) ----------------------------------------

__global__ __launch_bounds__(256) void gemm_qkv(const bf16_t* __restrict__ x,
                                                const bf16_t* __restrict__ Bq,
                                                const bf16_t* __restrict__ Bk,
                                                const bf16_t* __restrict__ Bv,
                                                const float* __restrict__ bq,
                                                const float* __restrict__ bk,
                                                const float* __restrict__ bv,
                                                bf16_t* __restrict__ qo,
                                                bf16_t* __restrict__ ko,
                                                bf16_t* __restrict__ vto,
                                                float* __restrict__ qn,
                                                float* __restrict__ kn) {
  __shared__ bf16_t As[2][64][72];
  __shared__ bf16_t Bs[2][64][72];
  const int z = blockIdx.z;
  const bf16_t* B = z == 0 ? Bq : z == 1 ? Bk : Bv;
  const float* bias = z == 0 ? bq : z == 1 ? bk : bv;
  const int tid = threadIdx.x, wid = tid >> 6, lane = tid & 63;
  const int c = lane & 15, hi = lane >> 4;
  const int m0 = blockIdx.y * 64, n0 = blockIdx.x * 64;
  Tile2 at, bt;
  tile_load(x + (size_t)m0 * DIM, DIM, at, tid);
  tile_load(B + (size_t)n0 * DIM, DIM, bt, tid);
  f32x4 acc[4] = {};
  for (int kk = 0; kk < 12; ++kk) {
    tile_write(As[kk & 1], at, tid);
    tile_write(Bs[kk & 1], bt, tid);
    __syncthreads();
    if (kk < 11) {
      tile_load(x + (size_t)m0 * DIM + (kk + 1) * 64, DIM, at, tid);
      tile_load(B + (size_t)n0 * DIM + (kk + 1) * 64, DIM, bt, tid);
    }
    mfma_nt64(As[kk & 1], Bs[kk & 1], wid, lane, acc);
    __syncthreads();
  }
  const int r0 = wid * 16 + hi * 4;
  float ss[4] = {0.f, 0.f, 0.f, 0.f};
#pragma unroll
  for (int nt = 0; nt < 4; ++nt) {
    int cc = n0 + nt * 16 + c;
    float bv_ = bias[cc];
    int h = cc >> 6, d = cc & 63;
#pragma unroll
    for (int r = 0; r < 4; ++r) {
      int mm = m0 + r0 + r;
      float val = acc[nt][r] + bv_;
      if (z == 2) {
        vto[(size_t)cc * L_SEQ + mm] = (bf16_t)val;
      } else {
        bf16_t* out = z == 0 ? qo : ko;
        out[((size_t)h * L_SEQ + mm) * 64 + d] = (bf16_t)val;
        ss[r] = fmaf(val, val, ss[r]);
      }
    }
  }
  if (z < 2) {
#pragma unroll
    for (int s = 1; s < 16; s <<= 1)
#pragma unroll
      for (int r = 0; r < 4; ++r) ss[r] += __shfl_xor(ss[r], s);
    if (c == 0) {
      float* norm = z == 0 ? qn : kn;
      int h = n0 >> 6;
#pragma unroll
      for (int r = 0; r < 4; ++r) norm[h * L_SEQ + m0 + r0 + r] = ss[r];
    }
  }
}

__global__ __launch_bounds__(256) void gemm_out(const bf16_t* __restrict__ A,
                                                const bf16_t* __restrict__ B,
                                                const float* __restrict__ bias,
                                                float* __restrict__ out) {
  __shared__ bf16_t As[2][64][72];
  __shared__ bf16_t Bs[2][64][72];
  const int tid = threadIdx.x, wid = tid >> 6, lane = tid & 63;
  const int c = lane & 15, hi = lane >> 4;
  const int m0 = blockIdx.y * 64, n0 = blockIdx.x * 64;
  Tile2 at, bt;
  tile_load(A + (size_t)m0 * DIM, DIM, at, tid);
  tile_load(B + (size_t)n0 * DIM, DIM, bt, tid);
  f32x4 acc[4] = {};
  for (int kk = 0; kk < 12; ++kk) {
    tile_write(As[kk & 1], at, tid);
    tile_write(Bs[kk & 1], bt, tid);
    __syncthreads();
    if (kk < 11) {
      tile_load(A + (size_t)m0 * DIM + (kk + 1) * 64, DIM, at, tid);
      tile_load(B + (size_t)n0 * DIM + (kk + 1) * 64, DIM, bt, tid);
    }
    mfma_nt64(As[kk & 1], Bs[kk & 1], wid, lane, acc);
    __syncthreads();
  }
  const int r0 = wid * 16 + hi * 4;
#pragma unroll
  for (int nt = 0; nt < 4; ++nt) {
    int cc = n0 + nt * 16 + c;
    float bv = bias[cc];
#pragma unroll
    for (int r = 0; r < 4; ++r)
      out[(size_t)(m0 + r0 + r) * DIM + cc] = acc[nt][r] + bv;
  }
}

// ---- pass 1: global max of dist_sq (swapped QK, Q in regs) ---------------

__global__ __launch_bounds__(256) void maxdist(const bf16_t* __restrict__ q,
                                               const bf16_t* __restrict__ k,
                                               const float* __restrict__ qn,
                                               const float* __restrict__ kn,
                                               float* __restrict__ blockmax) {
  __shared__ bf16_t Ks[2][64][72];
  __shared__ float wmax[4];
  const int it = blockIdx.x, jc = blockIdx.y, h = blockIdx.z;
  const int i0 = it * 64, jbase = jc * (L_SEQ / MDJ);
  const int tid = threadIdx.x, wid = tid >> 6, lane = tid & 63;
  const int c = lane & 15, hi = lane >> 4;
  bf16x8 qb[4][2];
  float aq[4];
#pragma unroll
  for (int nt = 0; nt < 4; ++nt) {
    const bf16_t* qr = q + ((size_t)h * L_SEQ + i0 + nt * 16 + c) * DKH;
    qb[nt][0] = ldg8(qr + hi * 8);
    qb[nt][1] = ldg8(qr + 32 + hi * 8);
    aq[nt] = qn[h * L_SEQ + i0 + nt * 16 + c];
  }
  Tile2 kt;
  tile_load(k + ((size_t)h * L_SEQ + jbase) * DKH, DKH, kt, tid);
  float m = 0.f;
  const int NT = L_SEQ / MDJ / 64;
  for (int t = 0; t < NT; ++t) {
    tile_write(Ks[t & 1], kt, tid);
    if (t < NT - 1)
      tile_load(k + ((size_t)h * L_SEQ + jbase + (t + 1) * 64) * DKH, DKH, kt, tid);
    __syncthreads();
    f32x4 acc[4] = {};
#pragma unroll
    for (int ks = 0; ks < 2; ++ks) {
      bf16x8 a = *(const bf16x8*)&Ks[t & 1][wid * 16 + c][ks * 32 + hi * 8];
#pragma unroll
      for (int nt = 0; nt < 4; ++nt) acc[nt] = mfma16(a, qb[nt][ks], acc[nt]);
    }
    f32x4 knj = *(const f32x4*)&kn[h * L_SEQ + jbase + t * 64 + wid * 16 + hi * 4];
#pragma unroll
    for (int nt = 0; nt < 4; ++nt)
#pragma unroll
      for (int r = 0; r < 4; ++r)
        m = fmaxf(m, fmaf(-2.f, acc[nt][r], aq[nt] + knj[r]));
  }
#pragma unroll
  for (int s = 1; s < 64; s <<= 1) m = fmaxf(m, __shfl_xor(m, s));
  if (lane == 0) wmax[wid] = m;
  __syncthreads();
  if (tid == 0) {
    float bm = fmaxf(fmaxf(wmax[0], wmax[1]), fmaxf(wmax[2], wmax[3]));
    blockmax[(h * MDJ + jc) * (L_SEQ / 64) + it] = fmaxf(bm, 0.f) * (1.f / 64.f);
  }
}

__global__ void reduce_dmax(const float* __restrict__ blockmax, float* __restrict__ dmax) {
  __shared__ float wm[2];
  const int h = blockIdx.x, tid = threadIdx.x, lane = tid & 63, wid = tid >> 6;
  float m = blockmax[h * 128 + tid];
#pragma unroll
  for (int s = 1; s < 64; s <<= 1) m = fmaxf(m, __shfl_xor(m, s));
  if (lane == 0) wm[wid] = m;
  __syncthreads();
  if (tid == 0) dmax[h] = fmaxf(wm[0], wm[1]);
}

// ---- pass 2: partial den + partial ctx^T (swapped QK) --------------------

__global__ __launch_bounds__(256) void fusedctx(const bf16_t* __restrict__ q,
                                                const bf16_t* __restrict__ k,
                                                const bf16_t* __restrict__ vt,
                                                const float* __restrict__ qn,
                                                const float* __restrict__ kn,
                                                const float* __restrict__ dmax,
                                                const float* __restrict__ theta,
                                                float* __restrict__ denP,
                                                float* __restrict__ ctxP, int JC) {
  __shared__ bf16_t Ks[2][64][72];
  __shared__ bf16_t Vs[2][64][72];
  __shared__ bf16_t Ws[64][72];
  __shared__ float denW[4][64];
  const int it = blockIdx.x, jc = blockIdx.y, h = blockIdx.z;
  const int i0 = it * 64;
  const int JLEN = L_SEQ / JC, jbase = jc * JLEN;
  const int tid = threadIdx.x, wid = tid >> 6, lane = tid & 63;
  const int c = lane & 15, hi = lane >> 4;
  const float sc = __expf(theta[h]) * (1.f / 64.f) / (dmax[h] + 1e-6f);
  const float twosc = 2.f * sc;
  bf16x8 qb[4][2];
  float naq[4];
#pragma unroll
  for (int nt = 0; nt < 4; ++nt) {
    const bf16_t* qr = q + ((size_t)h * L_SEQ + i0 + nt * 16 + c) * DKH;
    qb[nt][0] = ldg8(qr + hi * 8);
    qb[nt][1] = ldg8(qr + 32 + hi * 8);
    naq[nt] = -sc * qn[h * L_SEQ + i0 + nt * 16 + c];
  }
  Tile2 kt, vtr;
  tile_load(k + ((size_t)h * L_SEQ + jbase) * DKH, DKH, kt, tid);
  tile_load(vt + (size_t)h * DKH * L_SEQ + jbase, L_SEQ, vtr, tid);
  float psum[4] = {0.f, 0.f, 0.f, 0.f};
  f32x4 cacc[4] = {};
  const int NT = JLEN / 64;
  for (int t = 0; t < NT; ++t) {
    tile_write(Ks[t & 1], kt, tid);
    tile_write(Vs[t & 1], vtr, tid);
    if (t < NT - 1) {
      tile_load(k + ((size_t)h * L_SEQ + jbase + (t + 1) * 64) * DKH, DKH, kt, tid);
      tile_load(vt + (size_t)h * DKH * L_SEQ + jbase + (t + 1) * 64, L_SEQ, vtr, tid);
    }
    __syncthreads();
    f32x4 acc[4] = {};
#pragma unroll
    for (int ks = 0; ks < 2; ++ks) {
      bf16x8 a = *(const bf16x8*)&Ks[t & 1][wid * 16 + c][ks * 32 + hi * 8];
#pragma unroll
      for (int nt = 0; nt < 4; ++nt) acc[nt] = mfma16(a, qb[nt][ks], acc[nt]);
    }
    f32x4 knj = *(const f32x4*)&kn[h * L_SEQ + jbase + t * 64 + wid * 16 + hi * 4];
    f32x4 sknj = knj * sc;
#pragma unroll
    for (int nt = 0; nt < 4; ++nt) {
      bf16x4 wp;
#pragma unroll
      for (int r = 0; r < 4; ++r) {
        float tt = fminf(fmaf(twosc, acc[nt][r], naq[nt] - sknj[r]), 0.f);
        float w = __expf(__expf(tt));      // in (0, e]
        psum[nt] += w;
        wp[r] = (bf16_t)w;
      }
      *(bf16x4*)&Ws[nt * 16 + c][wid * 16 + hi * 4] = wp;
    }
    __syncthreads();
#pragma unroll
    for (int ks = 0; ks < 2; ++ks) {
      bf16x8 a = *(const bf16x8*)&Vs[t & 1][wid * 16 + c][ks * 32 + hi * 8];
#pragma unroll
      for (int nt = 0; nt < 4; ++nt) {
        bf16x8 b = *(const bf16x8*)&Ws[nt * 16 + c][ks * 32 + hi * 8];
        cacc[nt] = mfma16(a, b, cacc[nt]);
      }
    }
  }
#pragma unroll
  for (int nt = 0; nt < 4; ++nt) {
    psum[nt] += __shfl_xor(psum[nt], 16);
    psum[nt] += __shfl_xor(psum[nt], 32);
  }
  if (lane < 16)
#pragma unroll
    for (int nt = 0; nt < 4; ++nt) denW[wid][nt * 16 + lane] = psum[nt];
  __syncthreads();
  if (tid < 64)
    denP[(size_t)(h * JC + jc) * L_SEQ + i0 + tid] =
        denW[0][tid] + denW[1][tid] + denW[2][tid] + denW[3][tid];
  float* P = ctxP + ((size_t)(h * JC + jc) * 32 + it) * 4096;
#pragma unroll
  for (int nt = 0; nt < 4; ++nt)
    *(f32x4*)&P[(nt * 16 + c) * 64 + wid * 16 + hi * 4] = cacc[nt];
}

__global__ __launch_bounds__(256) void ctx_combine(const float* __restrict__ denP,
                                                   const float* __restrict__ ctxP,
                                                   float* __restrict__ den,
                                                   bf16_t* __restrict__ ctx, int JC) {
  __shared__ float invL[64];
  const int it = blockIdx.x, h = blockIdx.y, tid = threadIdx.x;
  const int i0 = it * 64;
  if (tid < 64) {
    float d0 = 0.f;
    for (int jc = 0; jc < JC; ++jc)
      d0 += denP[(size_t)(h * JC + jc) * L_SEQ + i0 + tid];
    den[h * L_SEQ + i0 + tid] = d0;
    invL[tid] = 1.f / d0;
  }
  __syncthreads();
  const int il = tid >> 2, db = (tid & 3) * 16;
  const float inv = invL[il];
  bf16_t* dst = ctx + (size_t)(i0 + il) * DIM + h * 64 + db;
#pragma unroll
  for (int half = 0; half < 2; ++half) {
    bf16x8 o;
#pragma unroll
    for (int e = 0; e < 2; ++e) {
      f32x4 v = {0.f, 0.f, 0.f, 0.f};
      for (int jc = 0; jc < JC; ++jc)
        v += *(const f32x4*)&ctxP[((size_t)(h * JC + jc) * 32 + it) * 4096 +
                                  il * 64 + db + half * 8 + e * 4];
#pragma unroll
      for (int j = 0; j < 4; ++j) o[e * 4 + j] = (bf16_t)(v[j] * inv);
    }
    *(bf16x8*)&dst[half * 8] = o;
  }
}

// ---- pass 3: out1 = mean over heads --------------------------------------
// 64i x 64j tile, 256 thr. BOTH Q and K cooperatively staged, double-buffered
// LDS (36.9 KB -> 4 blocks/CU), register prefetch of head h+1, 1 sync/head.
// Swapped MFMA (A=K from LDS, B=Q from LDS) keeps kn loads + out1 stores f32x4.
__global__ __launch_bounds__(256) void attnmean(const bf16_t* __restrict__ q,
                                                const bf16_t* __restrict__ k,
                                                const float* __restrict__ qn,
                                                const float* __restrict__ kn,
                                                const float* __restrict__ dmax,
                                                const float* __restrict__ theta,
                                                const float* __restrict__ den,
                                                float* __restrict__ out1) {
  __shared__ bf16_t Qs[2][64][72];
  __shared__ bf16_t Ks[2][64][72];
  const int j0 = blockIdx.x * 64, i0 = blockIdx.y * 64;
  const int tid = threadIdx.x, wid = tid >> 6, lane = tid & 63;
  const int c = lane & 15, hi = lane >> 4;
  Tile2 qt, kt;
  tile_load(q + (size_t)i0 * DKH, DKH, qt, tid);       // h = 0
  tile_load(k + (size_t)j0 * DKH, DKH, kt, tid);
  f32x4 macc[4] = {};
  for (int h = 0; h < NH; ++h) {
    const int b = h & 1;
    tile_write(Qs[b], qt, tid);
    tile_write(Ks[b], kt, tid);
    __syncthreads();
    if (h < NH - 1) {
      tile_load(q + ((size_t)(h + 1) * L_SEQ + i0) * DKH, DKH, qt, tid);
      tile_load(k + ((size_t)(h + 1) * L_SEQ + j0) * DKH, DKH, kt, tid);
    }
    const float sc = __expf(theta[h]) * (1.f / 64.f) / (dmax[h] + 1e-6f);
    const float twosc = 2.f * sc;
    f32x4 acc[4] = {};
#pragma unroll
    for (int ks = 0; ks < 2; ++ks) {
      bf16x8 a = *(const bf16x8*)&Ks[b][wid * 16 + c][ks * 32 + hi * 8];
#pragma unroll
      for (int nt = 0; nt < 4; ++nt) {
        bf16x8 bq_ = *(const bf16x8*)&Qs[b][nt * 16 + c][ks * 32 + hi * 8];
        acc[nt] = mfma16(a, bq_, acc[nt]);
      }
    }
    f32x4 knj = *(const f32x4*)&kn[h * L_SEQ + j0 + wid * 16 + hi * 4];
    f32x4 sknj = knj * sc;
#pragma unroll
    for (int nt = 0; nt < 4; ++nt) {
      float naq = -sc * qn[h * L_SEQ + i0 + nt * 16 + c];
      float inv = 1.f / den[h * L_SEQ + i0 + nt * 16 + c];
#pragma unroll
      for (int r = 0; r < 4; ++r) {
        float tt = fminf(fmaf(twosc, acc[nt][r], naq - sknj[r]), 0.f);
        float w = __expf(__expf(tt));
        macc[nt][r] = fmaf(w, inv, macc[nt][r]);
      }
    }
    __syncthreads();
  }
#pragma unroll
  for (int nt = 0; nt < 4; ++nt) {
    f32x4 o = macc[nt] * (1.f / 12.f);
    *(f32x4*)&out1[(size_t)(i0 + nt * 16 + c) * L_SEQ + j0 + wid * 16 + hi * 4] = o;
  }
}

// ---- launch -------------------------------------------------------------

extern "C" void kernel_launch(void* const* d_in, const int* in_sizes, int n_in,
                              void* d_out, int out_size, void* d_ws, size_t ws_size,
                              hipStream_t stream) {
  const float* x = (const float*)d_in[0];
  const float* Wq = (const float*)d_in[1];
  const float* bq = (const float*)d_in[2];
  const float* Wk = (const float*)d_in[3];
  const float* bk = (const float*)d_in[4];
  const float* Wv = (const float*)d_in[5];
  const float* bv = (const float*)d_in[6];
  const float* Wo = (const float*)d_in[7];
  const float* bo = (const float*)d_in[8];
  const float* theta = (const float*)d_in[9];

  bf16_t* x_bf = (bf16_t*)d_ws;
  bf16_t* Wq_bf = x_bf + (size_t)L_SEQ * DIM;
  bf16_t* Wk_bf = Wq_bf + (size_t)DIM * DIM;
  bf16_t* Wv_bf = Wk_bf + (size_t)DIM * DIM;
  bf16_t* Wo_bf = Wv_bf + (size_t)DIM * DIM;
  bf16_t* q_bf = Wo_bf + (size_t)DIM * DIM;
  bf16_t* k_bf = q_bf + (size_t)NH * L_SEQ * DKH;
  bf16_t* vt_bf = k_bf + (size_t)NH * L_SEQ * DKH;
  bf16_t* ctx_bf = vt_bf + (size_t)NH * L_SEQ * DKH;
  float* qn = (float*)(ctx_bf + (size_t)L_SEQ * DIM);
  float* kn = qn + NH * L_SEQ;
  float* den = kn + NH * L_SEQ;
  float* dmax = den + NH * L_SEQ;
  float* blockmax = dmax + 64;                 // NH*MDJ*32 = 1536
  float* denP = blockmax + 2048;               // JC*NH*L_SEQ <= 98304
  float* ctxP = denP + 4 * NH * L_SEQ;         // JC*NH*32*4096 fp32

  size_t fixed_bytes = (size_t)((char*)ctxP - (char*)d_ws);
  int JC = (fixed_bytes + (size_t)4 * NH * 32 * 4096 * 4 <= ws_size) ? 4 : 2;

  float* out0 = (float*)d_out;
  float* out1 = out0 + (size_t)L_SEQ * DIM;

  cast_x<<<(L_SEQ * DIM / 4 + 255) / 256, 256, 0, stream>>>(x, x_bf, L_SEQ * DIM / 4);
  cast_w4<<<dim3((DIM * DIM / 4 + 255) / 256, 4), 256, 0, stream>>>(
      Wq, Wk, Wv, Wo, Wq_bf, Wk_bf, Wv_bf, Wo_bf, DIM * DIM / 4);

  gemm_qkv<<<dim3(DIM / 64, L_SEQ / 64, 3), 256, 0, stream>>>(
      x_bf, Wq_bf, Wk_bf, Wv_bf, bq, bk, bv, q_bf, k_bf, vt_bf, qn, kn);

  maxdist<<<dim3(L_SEQ / 64, MDJ, NH), 256, 0, stream>>>(q_bf, k_bf, qn, kn, blockmax);
  reduce_dmax<<<NH, 128, 0, stream>>>(blockmax, dmax);

  fusedctx<<<dim3(L_SEQ / 64, JC, NH), 256, 0, stream>>>(q_bf, k_bf, vt_bf, qn, kn,
                                                         dmax, theta, denP, ctxP, JC);
  ctx_combine<<<dim3(L_SEQ / 64, NH), 256, 0, stream>>>(denP, ctxP, den, ctx_bf, JC);

  attnmean<<<dim3(L_SEQ / 64, L_SEQ / 64), 256, 0, stream>>>(q_bf, k_bf, qn, kn, dmax,
                                                             theta, den, out1);
  gemm_out<<<dim3(DIM / 64, L_SEQ / 64), 256, 0, stream>>>(ctx_bf, Wo_bf, bo, out0);
}